// Round 1
// baseline (2404.851 us; speedup 1.0000x reference)
//
#include <hip/hip_runtime.h>
#include <hip/hip_bf16.h>

// ---------------- problem constants ----------------
#define NN 100000      // nodes
#define NE 800000      // edges
#define DIN 128
#define DCAT 384
#define BN_EPS 1e-5

// ---------------- preprocessing kernels ----------------

__global__ void count_deg_k(const int* __restrict__ ei, int* __restrict__ deg) {
    int i = blockIdx.x * blockDim.x + threadIdx.x;
    if (i < NE) atomicAdd(&deg[ei[NE + i]], 1);   // col = ei[1][e]
}

__global__ void dinv_k(const int* __restrict__ deg, float* __restrict__ dinv) {
    int i = blockIdx.x * blockDim.x + threadIdx.x;
    if (i < NN) {
        int d = deg[i];
        dinv[i] = (d > 0) ? rsqrtf((float)d) : 0.f;
    }
}

// exclusive scan over deg -> ptr, per-block stage
__global__ void scan1_k(const int* __restrict__ deg, int* __restrict__ out,
                        int* __restrict__ bsum) {
    __shared__ int s[1024];
    int i = blockIdx.x * 1024 + threadIdx.x;
    int v = (i < NN) ? deg[i] : 0;
    s[threadIdx.x] = v;
    __syncthreads();
    for (int off = 1; off < 1024; off <<= 1) {
        int t = (threadIdx.x >= off) ? s[threadIdx.x - off] : 0;
        __syncthreads();
        s[threadIdx.x] += t;
        __syncthreads();
    }
    if (i < NN) out[i] = s[threadIdx.x] - v;   // exclusive
    if (threadIdx.x == 1023) bsum[blockIdx.x] = s[1023];
}

__global__ void scan2_k(int* __restrict__ bsum, int nb) {
    if (threadIdx.x == 0) {
        int acc = 0;
        for (int b = 0; b < nb; ++b) { int v = bsum[b]; bsum[b] = acc; acc += v; }
    }
}

__global__ void scan3_k(int* __restrict__ ptr, int* __restrict__ cursor,
                        const int* __restrict__ bsum) {
    int i = blockIdx.x * 1024 + threadIdx.x;
    if (i < NN) {
        int p = ptr[i] + bsum[blockIdx.x];
        ptr[i] = p;
        cursor[i] = p;
    }
    if (i == NN) ptr[NN] = NE;
}

__global__ void scatter_k(const int* __restrict__ ei, const float* __restrict__ dinv,
                          int* __restrict__ cursor, int* __restrict__ crow,
                          float* __restrict__ cw) {
    int i = blockIdx.x * blockDim.x + threadIdx.x;
    if (i >= NE) return;
    int r = ei[i];
    int c = ei[NE + i];
    int p = atomicAdd(&cursor[c], 1);
    crow[p] = r;
    cw[p] = dinv[r] * dinv[c];
}

// ---------------- fused 3-matrix GEMM:  T = X @ [W0|W1|W2] + b ----------------
// X: NN x K (row-major, pitch K).  W: (3, K, 128).  bias: (3, 128).
// group j=0 -> o0 (pitch 384), j=1 -> o1 (pitch 128), j=2 -> o2 (pitch 128).
#define BM 128
#define BNW 64
#define BKK 32

__global__ __launch_bounds__(256) void gemm3_k(
    const float* __restrict__ X, int K,
    const float* __restrict__ W, const float* __restrict__ bias,
    float* __restrict__ o0, float* __restrict__ o1, float* __restrict__ o2) {
    __shared__ float As[BKK][BM + 8];   // +8 pad keeps float4 alignment, breaks conflicts
    __shared__ float Bs[BKK][BNW];

    int cb = blockIdx.y;          // 0..5
    int j  = cb >> 1;             // weight group
    int c0 = (cb & 1) * 64;       // column offset inside group
    const float* Wj = W + (size_t)j * K * 128;
    int m0 = blockIdx.x * BM;
    int t  = threadIdx.x;
    int tx = t & 15, ty = t >> 4;

    float acc[8][4];
#pragma unroll
    for (int a = 0; a < 8; ++a)
#pragma unroll
        for (int b = 0; b < 4; ++b) acc[a][b] = 0.f;

    for (int kb = 0; kb < K; kb += BKK) {
        // A tile: 128 rows x 32 k, float4 loads, store transposed
#pragma unroll
        for (int i = 0; i < 4; ++i) {
            int lin = t + i * 256;        // 0..1023
            int row = lin >> 3;
            int kq  = lin & 7;
            int gr  = m0 + row;
            if (gr >= NN) gr = NN - 1;
            float4 a4 = *(const float4*)(X + (size_t)gr * K + kb + kq * 4);
            As[kq * 4 + 0][row] = a4.x;
            As[kq * 4 + 1][row] = a4.y;
            As[kq * 4 + 2][row] = a4.z;
            As[kq * 4 + 3][row] = a4.w;
        }
        // B tile: 32 k x 64 cols
#pragma unroll
        for (int i = 0; i < 8; ++i) {
            int lin = t + i * 256;        // 0..2047
            int nn  = lin & 63;
            int kk  = lin >> 6;
            Bs[kk][nn] = Wj[(size_t)(kb + kk) * 128 + c0 + nn];
        }
        __syncthreads();
#pragma unroll
        for (int k = 0; k < BKK; ++k) {
            float4 b4 = *(const float4*)&Bs[k][tx * 4];
            float4 a0 = *(const float4*)&As[k][ty * 8];
            float4 a1 = *(const float4*)&As[k][ty * 8 + 4];
            float a[8] = {a0.x, a0.y, a0.z, a0.w, a1.x, a1.y, a1.z, a1.w};
            float b[4] = {b4.x, b4.y, b4.z, b4.w};
#pragma unroll
            for (int mi = 0; mi < 8; ++mi)
#pragma unroll
                for (int ni = 0; ni < 4; ++ni) acc[mi][ni] += a[mi] * b[ni];
        }
        __syncthreads();
    }

    float4 bb = *(const float4*)(bias + j * 128 + c0 + tx * 4);
    float* dst = (j == 0) ? o0 : ((j == 1) ? o1 : o2);
    int pitch  = (j == 0) ? DCAT : 128;
#pragma unroll
    for (int mi = 0; mi < 8; ++mi) {
        int gr = m0 + ty * 8 + mi;
        if (gr < NN) {
            float4 v;
            v.x = acc[mi][0] + bb.x;
            v.y = acc[mi][1] + bb.y;
            v.z = acc[mi][2] + bb.z;
            v.w = acc[mi][3] + bb.w;
            *(float4*)(dst + (size_t)gr * pitch + c0 + tx * 4) = v;
        }
    }
}

// ---------------- pull-mode SpMM: out[i] = sum_e w_e * xin[row_e], one wave/node ----
__global__ __launch_bounds__(256) void spmm_k(
    const int* __restrict__ ptr, const int* __restrict__ rows,
    const float* __restrict__ wv, const float* __restrict__ xin, int pin,
    float* __restrict__ xout, int pout) {
    int wid  = (blockIdx.x * blockDim.x + threadIdx.x) >> 6;
    int lane = threadIdx.x & 63;
    if (wid >= NN) return;
    int e0 = ptr[wid], e1 = ptr[wid + 1];
    float2 acc = make_float2(0.f, 0.f);
    for (int e = e0; e < e1; ++e) {
        int r   = rows[e];
        float w = wv[e];
        float2 v = ((const float2*)(xin + (size_t)r * pin))[lane];
        acc.x += w * v.x;
        acc.y += w * v.y;
    }
    ((float2*)(xout + (size_t)wid * pout))[lane] = acc;
}

// ---------------- BatchNorm (feature-wise over 100k rows) + ReLU ----------------
#define BN_ROWS 256
#define BN_NBLK ((NN + BN_ROWS - 1) / BN_ROWS)   // 391

__global__ void bn_stats1_k(const float* __restrict__ H, float* __restrict__ partial) {
    int c  = threadIdx.x;                 // 384 threads
    int r0 = blockIdx.x * BN_ROWS;
    int r1 = min(r0 + BN_ROWS, NN);
    float s = 0.f, s2 = 0.f;
    for (int r = r0; r < r1; ++r) {
        float v = H[(size_t)r * DCAT + c];
        s  += v;
        s2 += v * v;
    }
    partial[blockIdx.x * 768 + c]       = s;
    partial[blockIdx.x * 768 + 384 + c] = s2;
}

__global__ void bn_finalize_k(const float* __restrict__ partial,
                              const float* __restrict__ g, const float* __restrict__ b,
                              float2* __restrict__ coef) {
    int c = threadIdx.x;                  // 384 threads
    double s = 0.0, s2 = 0.0;
    for (int i = 0; i < BN_NBLK; ++i) {
        s  += (double)partial[i * 768 + c];
        s2 += (double)partial[i * 768 + 384 + c];
    }
    double mu  = s / (double)NN;
    double var = s2 / (double)NN - mu * mu;
    double inv = 1.0 / sqrt(var + (double)BN_EPS);
    float scale = (float)((double)g[c] * inv);
    float shift = (float)((double)b[c] - mu * (double)g[c] * inv);
    coef[c] = make_float2(scale, shift);
}

__global__ void bn_apply_k(float* __restrict__ H, const float2* __restrict__ coef) {
    unsigned i = blockIdx.x * blockDim.x + threadIdx.x;   // over N*96 float4s
    if (i >= (unsigned)NN * 96u) return;
    float4 v = ((float4*)H)[i];
    int c4 = (int)(i % 96u) * 4;
    float2 s0 = coef[c4 + 0];
    float2 s1 = coef[c4 + 1];
    float2 s2 = coef[c4 + 2];
    float2 s3 = coef[c4 + 3];
    v.x = fmaxf(v.x * s0.x + s0.y, 0.f);
    v.y = fmaxf(v.y * s1.x + s1.y, 0.f);
    v.z = fmaxf(v.z * s2.x + s2.y, 0.f);
    v.w = fmaxf(v.w * s3.x + s3.y, 0.f);
    ((float4*)H)[i] = v;
}

// ---------------- host-side orchestration ----------------

static void run_layer(const float* X, int K, const float* W, const float* bias,
                      float* Hout, float* tmpA, float* tmpB,
                      const int* ptr, const int* crow, const float* cw,
                      hipStream_t stream) {
    dim3 g((NN + BM - 1) / BM, 6);
    gemm3_k<<<g, 256, 0, stream>>>(X, K, W, bias, Hout, tmpA, tmpB);
    int sg = (NN * 64 + 255) / 256;   // one wave per node, 4 nodes/block
    spmm_k<<<sg, 256, 0, stream>>>(ptr, crow, cw, tmpA, 128, Hout + 128, DCAT);
    spmm_k<<<sg, 256, 0, stream>>>(ptr, crow, cw, tmpB, 128, tmpA, 128);
    spmm_k<<<sg, 256, 0, stream>>>(ptr, crow, cw, tmpA, 128, Hout + 256, DCAT);
}

static void run_bn(float* H, const float* g, const float* b,
                   float* partial, float2* coef, hipStream_t stream) {
    bn_stats1_k<<<BN_NBLK, 384, 0, stream>>>(H, partial);
    bn_finalize_k<<<1, 384, 0, stream>>>(partial, g, b, coef);
    unsigned n4 = (unsigned)NN * 96u;
    bn_apply_k<<<(n4 + 255) / 256, 256, 0, stream>>>(H, coef);
}

extern "C" void kernel_launch(void* const* d_in, const int* in_sizes, int n_in,
                              void* d_out, int out_size, void* d_ws, size_t ws_size,
                              hipStream_t stream) {
    const float* x        = (const float*)d_in[0];
    const int*   ei       = (const int*)d_in[1];
    const float* W0       = (const float*)d_in[2];
    const float* b0       = (const float*)d_in[3];
    const float* W1       = (const float*)d_in[4];
    const float* b1       = (const float*)d_in[5];
    const float* W2       = (const float*)d_in[6];
    const float* b2       = (const float*)d_in[7];
    const float* bn_gamma = (const float*)d_in[8];
    const float* bn_beta  = (const float*)d_in[9];
    float* out = (float*)d_out;

    // workspace carve-up (512B aligned slabs)
    char* p = (char*)d_ws;
    auto alloc = [&](size_t bytes) -> void* {
        void* r = (void*)p;
        p += (bytes + 511) & ~(size_t)511;
        return r;
    };
    float* Hws     = (float*)alloc((size_t)NN * DCAT * 4);
    float* tmpA    = (float*)alloc((size_t)NN * 128 * 4);
    float* tmpB    = (float*)alloc((size_t)NN * 128 * 4);
    int*   deg     = (int*)alloc((size_t)NN * 4);
    float* dinv    = (float*)alloc((size_t)NN * 4);
    int*   ptr     = (int*)alloc((size_t)(NN + 1) * 4);
    int*   cursor  = (int*)alloc((size_t)NN * 4);
    int*   bsum    = (int*)alloc(1024);
    int*   crow    = (int*)alloc((size_t)NE * 4);
    float* cw      = (float*)alloc((size_t)NE * 4);
    float* partial = (float*)alloc((size_t)BN_NBLK * 768 * 4);
    float2* coef   = (float2*)alloc(384 * 8);

    // ---- graph preprocessing: degrees, norm weights, CSR by destination ----
    hipMemsetAsync(deg, 0, (size_t)NN * 4, stream);
    count_deg_k<<<(NE + 255) / 256, 256, 0, stream>>>(ei, deg);
    dinv_k<<<(NN + 255) / 256, 256, 0, stream>>>(deg, dinv);
    int nsb = (NN + 1023) / 1024;   // 98
    scan1_k<<<nsb, 1024, 0, stream>>>(deg, ptr, bsum);
    scan2_k<<<1, 64, 0, stream>>>(bsum, nsb);
    scan3_k<<<nsb, 1024, 0, stream>>>(ptr, cursor, bsum);
    scatter_k<<<(NE + 255) / 256, 256, 0, stream>>>(ei, dinv, cursor, crow, cw);

    // ---- layer 0: x (N x 128) -> d_out (N x 384), BN+ReLU in place ----
    run_layer(x, DIN, W0, b0, out, tmpA, tmpB, ptr, crow, cw, stream);
    run_bn(out, bn_gamma, bn_beta, partial, coef, stream);

    // ---- layer 1: d_out -> Hws, BN+ReLU in place ----
    run_layer(out, DCAT, W1, b1, Hws, tmpA, tmpB, ptr, crow, cw, stream);
    run_bn(Hws, bn_gamma + DCAT, bn_beta + DCAT, partial, coef, stream);

    // ---- layer 2: Hws -> d_out (raw concat, no BN) ----
    run_layer(Hws, DCAT, W2, b2, out, tmpA, tmpB, ptr, crow, cw, stream);
}

// Round 2
// 1917.610 us; speedup vs baseline: 1.2541x; 1.2541x over previous
//
#include <hip/hip_runtime.h>
#include <hip/hip_bf16.h>

// ---------------- problem constants ----------------
#define NN 100000      // nodes
#define NE 800000      // edges
#define DIN 128
#define DCAT 384
#define BN_EPS 1e-5

typedef __attribute__((ext_vector_type(8))) short bf16x8;
typedef __attribute__((ext_vector_type(4))) float f32x4;

// ---------------- preprocessing kernels ----------------

__global__ void count_deg_k(const int* __restrict__ ei, int* __restrict__ deg) {
    int i = blockIdx.x * blockDim.x + threadIdx.x;
    if (i < NE) atomicAdd(&deg[ei[NE + i]], 1);   // col = ei[1][e]
}

__global__ void dinv_k(const int* __restrict__ deg, float* __restrict__ dinv) {
    int i = blockIdx.x * blockDim.x + threadIdx.x;
    if (i < NN) {
        int d = deg[i];
        dinv[i] = (d > 0) ? rsqrtf((float)d) : 0.f;
    }
}

__global__ void scan1_k(const int* __restrict__ deg, int* __restrict__ out,
                        int* __restrict__ bsum) {
    __shared__ int s[1024];
    int i = blockIdx.x * 1024 + threadIdx.x;
    int v = (i < NN) ? deg[i] : 0;
    s[threadIdx.x] = v;
    __syncthreads();
    for (int off = 1; off < 1024; off <<= 1) {
        int t = (threadIdx.x >= off) ? s[threadIdx.x - off] : 0;
        __syncthreads();
        s[threadIdx.x] += t;
        __syncthreads();
    }
    if (i < NN) out[i] = s[threadIdx.x] - v;   // exclusive
    if (threadIdx.x == 1023) bsum[blockIdx.x] = s[1023];
}

__global__ void scan2_k(int* __restrict__ bsum, int nb) {
    if (threadIdx.x == 0) {
        int acc = 0;
        for (int b = 0; b < nb; ++b) { int v = bsum[b]; bsum[b] = acc; acc += v; }
    }
}

__global__ void scan3_k(int* __restrict__ ptr, int* __restrict__ cursor,
                        const int* __restrict__ bsum) {
    int i = blockIdx.x * 1024 + threadIdx.x;
    if (i < NN) {
        int p = ptr[i] + bsum[blockIdx.x];
        ptr[i] = p;
        cursor[i] = p;
    }
    if (i == NN) ptr[NN] = NE;
}

__global__ void scatter_k(const int* __restrict__ ei, const float* __restrict__ dinv,
                          int* __restrict__ cursor, int* __restrict__ crow,
                          float* __restrict__ cw) {
    int i = blockIdx.x * blockDim.x + threadIdx.x;
    if (i >= NE) return;
    int r = ei[i];
    int c = ei[NE + i];
    int p = atomicAdd(&cursor[c], 1);
    crow[p] = r;
    cw[p] = dinv[r] * dinv[c];
}

// ---------------- split-bf16 helpers ----------------
// hi = truncate(x) to bf16 (exact top 16 bits); lo = RNE-bf16(x - hi).
// Dropped lo*lo term is ~2^-16 relative -> near-fp32 GEMM accuracy.

__device__ inline void split_trunc(float x, short& hi, short& lo) {
    unsigned u = __builtin_bit_cast(unsigned, x);
    hi = (short)(u >> 16);
    float hf = __builtin_bit_cast(float, u & 0xFFFF0000u);
    __hip_bfloat16 l = __float2bfloat16(x - hf);
    lo = *reinterpret_cast<short*>(&l);
}

// pre-split + transpose weights:  W (3,K,128) -> Wt_hi/lo (3,128,384) [group][col][k]
__global__ void wsplit_k(const float* __restrict__ W, int K,
                         short* __restrict__ Wth, short* __restrict__ Wtl) {
    int i = blockIdx.x * 256 + threadIdx.x;
    if (i >= 3 * K * 128) return;
    int c = i & 127;
    int k = (i >> 7) % K;
    int j = i / (K * 128);
    short h, l;
    split_trunc(W[i], h, l);
    size_t o = (size_t)j * 128 * 384 + (size_t)c * 384 + k;
    Wth[o] = h;
    Wtl[o] = l;
}

// ---------------- MFMA split-bf16 GEMM: T = X @ [W0|W1|W2] + b ----------------
// grid = (3 groups, ceil(N/128)); block 256 = 4 waves; each block: 128 rows x 128 cols.
// Wave wv: 64x64 sub-tile at (wr, wc). LDS tiles [row][k] bf16, pitch 40 (80B, bank-spread).
#define GPITCH 40

__global__ __launch_bounds__(256, 2) void gemm3m_k(
    const float* __restrict__ X, int K,
    const short* __restrict__ Wth, const short* __restrict__ Wtl,
    const float* __restrict__ bias,
    float* __restrict__ o0, float* __restrict__ o1, float* __restrict__ o2) {
    __shared__ short As_h[128 * GPITCH];
    __shared__ short As_l[128 * GPITCH];
    __shared__ short Bs_h[128 * GPITCH];
    __shared__ short Bs_l[128 * GPITCH];

    const int j    = blockIdx.x;            // weight group 0..2
    const int m0   = blockIdx.y * 128;
    const int t    = threadIdx.x;
    const int lane = t & 63;
    const int wv   = t >> 6;
    const int wr   = (wv >> 1) * 64;        // wave row offset in block tile
    const int wc   = (wv & 1) * 64;         // wave col offset
    const int lr   = lane & 15;             // frag row/col index
    const int lk   = lane >> 4;             // frag k-group (0..3)

    const short* Wh = Wth + (size_t)j * 128 * 384;
    const short* Wl = Wtl + (size_t)j * 128 * 384;

    f32x4 acc[4][4];
#pragma unroll
    for (int a = 0; a < 4; ++a)
#pragma unroll
        for (int b = 0; b < 4; ++b) acc[a][b] = (f32x4){0.f, 0.f, 0.f, 0.f};

    for (int kb = 0; kb < K; kb += 32) {
        // ---- stage A: 128 rows x 32 k fp32 -> hi/lo bf16 in LDS ----
#pragma unroll
        for (int i = 0; i < 4; ++i) {
            int lin = t + i * 256;          // 0..1023
            int row = lin >> 3, kq = lin & 7;
            int gr = m0 + row;
            if (gr >= NN) gr = NN - 1;
            float4 a4 = *(const float4*)(X + (size_t)gr * K + kb + kq * 4);
            short h0, l0, h1, l1, h2, l2, h3, l3;
            split_trunc(a4.x, h0, l0);
            split_trunc(a4.y, h1, l1);
            split_trunc(a4.z, h2, l2);
            split_trunc(a4.w, h3, l3);
            *(short4*)&As_h[row * GPITCH + kq * 4] = make_short4(h0, h1, h2, h3);
            *(short4*)&As_l[row * GPITCH + kq * 4] = make_short4(l0, l1, l2, l3);
        }
        // ---- stage B: 128 cols x 32 k from pre-split transposed weights ----
#pragma unroll
        for (int i = 0; i < 4; ++i) {
            int lin = t + i * 256;
            int col = lin >> 3, kq = lin & 7;
            short4 bh = *(const short4*)(Wh + (size_t)col * 384 + kb + kq * 4);
            short4 bl = *(const short4*)(Wl + (size_t)col * 384 + kb + kq * 4);
            *(short4*)&Bs_h[col * GPITCH + kq * 4] = bh;
            *(short4*)&Bs_l[col * GPITCH + kq * 4] = bl;
        }
        __syncthreads();

        bf16x8 ah[4], al[4];
#pragma unroll
        for (int mr = 0; mr < 4; ++mr) {
            int r = wr + mr * 16 + lr;
            ah[mr] = *(const bf16x8*)&As_h[r * GPITCH + lk * 8];
            al[mr] = *(const bf16x8*)&As_l[r * GPITCH + lk * 8];
        }
#pragma unroll
        for (int nc = 0; nc < 4; ++nc) {
            int c = wc + nc * 16 + lr;
            bf16x8 bh = *(const bf16x8*)&Bs_h[c * GPITCH + lk * 8];
            bf16x8 bl = *(const bf16x8*)&Bs_l[c * GPITCH + lk * 8];
#pragma unroll
            for (int mr = 0; mr < 4; ++mr) {
                f32x4 a = acc[mr][nc];
                a = __builtin_amdgcn_mfma_f32_16x16x32_bf16(al[mr], bh, a, 0, 0, 0);
                a = __builtin_amdgcn_mfma_f32_16x16x32_bf16(ah[mr], bl, a, 0, 0, 0);
                a = __builtin_amdgcn_mfma_f32_16x16x32_bf16(ah[mr], bh, a, 0, 0, 0);
                acc[mr][nc] = a;
            }
        }
        __syncthreads();
    }

    float* dst;
    int pitch;
    if (j == 0)      { dst = o0; pitch = DCAT; }
    else if (j == 1) { dst = o1; pitch = 128; }
    else             { dst = o2; pitch = 128; }

#pragma unroll
    for (int nc = 0; nc < 4; ++nc) {
        int col = wc + nc * 16 + lr;
        float bv = bias[j * 128 + col];
#pragma unroll
        for (int mr = 0; mr < 4; ++mr) {
            f32x4 a = acc[mr][nc];
#pragma unroll
            for (int r = 0; r < 4; ++r) {
                int row = m0 + wr + mr * 16 + lk * 4 + r;
                if (row < NN) dst[(size_t)row * pitch + col] = a[r] + bv;
            }
        }
    }
}

// ---------------- pull-mode SpMM: out[i] = sum_e w_e * xin[row_e], one wave/node ----
__global__ __launch_bounds__(256) void spmm_k(
    const int* __restrict__ ptr, const int* __restrict__ rows,
    const float* __restrict__ wv, const float* __restrict__ xin, int pin,
    float* __restrict__ xout, int pout) {
    int wid  = (blockIdx.x * blockDim.x + threadIdx.x) >> 6;
    int lane = threadIdx.x & 63;
    if (wid >= NN) return;
    int e0 = ptr[wid], e1 = ptr[wid + 1];
    float2 acc = make_float2(0.f, 0.f);
    for (int e = e0; e < e1; ++e) {
        int r   = rows[e];
        float w = wv[e];
        float2 v = ((const float2*)(xin + (size_t)r * pin))[lane];
        acc.x += w * v.x;
        acc.y += w * v.y;
    }
    ((float2*)(xout + (size_t)wid * pout))[lane] = acc;
}

// ---------------- BatchNorm (feature-wise over 100k rows) + ReLU ----------------
#define BN_ROWS 256
#define BN_NBLK ((NN + BN_ROWS - 1) / BN_ROWS)   // 391

__global__ void bn_stats1_k(const float* __restrict__ H, float* __restrict__ partial) {
    int c  = threadIdx.x;                 // 384 threads
    int r0 = blockIdx.x * BN_ROWS;
    int r1 = min(r0 + BN_ROWS, NN);
    float s = 0.f, s2 = 0.f;
    for (int r = r0; r < r1; ++r) {
        float v = H[(size_t)r * DCAT + c];
        s  += v;
        s2 += v * v;
    }
    partial[blockIdx.x * 768 + c]       = s;
    partial[blockIdx.x * 768 + 384 + c] = s2;
}

__global__ void bn_finalize_k(const float* __restrict__ partial,
                              const float* __restrict__ g, const float* __restrict__ b,
                              float2* __restrict__ coef) {
    int c = threadIdx.x;                  // 384 threads
    double s = 0.0, s2 = 0.0;
    for (int i = 0; i < BN_NBLK; ++i) {
        s  += (double)partial[i * 768 + c];
        s2 += (double)partial[i * 768 + 384 + c];
    }
    double mu  = s / (double)NN;
    double var = s2 / (double)NN - mu * mu;
    double inv = 1.0 / sqrt(var + (double)BN_EPS);
    float scale = (float)((double)g[c] * inv);
    float shift = (float)((double)b[c] - mu * (double)g[c] * inv);
    coef[c] = make_float2(scale, shift);
}

__global__ void bn_apply_k(float* __restrict__ H, const float2* __restrict__ coef) {
    unsigned i = blockIdx.x * blockDim.x + threadIdx.x;   // over N*96 float4s
    if (i >= (unsigned)NN * 96u) return;
    float4 v = ((float4*)H)[i];
    int c4 = (int)(i % 96u) * 4;
    float2 s0 = coef[c4 + 0];
    float2 s1 = coef[c4 + 1];
    float2 s2 = coef[c4 + 2];
    float2 s3 = coef[c4 + 3];
    v.x = fmaxf(v.x * s0.x + s0.y, 0.f);
    v.y = fmaxf(v.y * s1.x + s1.y, 0.f);
    v.z = fmaxf(v.z * s2.x + s2.y, 0.f);
    v.w = fmaxf(v.w * s3.x + s3.y, 0.f);
    ((float4*)H)[i] = v;
}

// ---------------- host-side orchestration ----------------

static void run_layer(const float* X, int K, const float* W, const float* bias,
                      float* Hout, float* tmpA, float* tmpB,
                      short* Wth, short* Wtl,
                      const int* ptr, const int* crow, const float* cw,
                      hipStream_t stream) {
    int nw = 3 * K * 128;
    wsplit_k<<<(nw + 255) / 256, 256, 0, stream>>>(W, K, Wth, Wtl);
    dim3 g(3, (NN + 127) / 128);
    gemm3m_k<<<g, 256, 0, stream>>>(X, K, Wth, Wtl, bias, Hout, tmpA, tmpB);
    int sg = (NN * 64 + 255) / 256;   // one wave per node, 4 nodes/block
    spmm_k<<<sg, 256, 0, stream>>>(ptr, crow, cw, tmpA, 128, Hout + 128, DCAT);
    spmm_k<<<sg, 256, 0, stream>>>(ptr, crow, cw, tmpB, 128, tmpA, 128);
    spmm_k<<<sg, 256, 0, stream>>>(ptr, crow, cw, tmpA, 128, Hout + 256, DCAT);
}

static void run_bn(float* H, const float* g, const float* b,
                   float* partial, float2* coef, hipStream_t stream) {
    bn_stats1_k<<<BN_NBLK, 384, 0, stream>>>(H, partial);
    bn_finalize_k<<<1, 384, 0, stream>>>(partial, g, b, coef);
    unsigned n4 = (unsigned)NN * 96u;
    bn_apply_k<<<(n4 + 255) / 256, 256, 0, stream>>>(H, coef);
}

extern "C" void kernel_launch(void* const* d_in, const int* in_sizes, int n_in,
                              void* d_out, int out_size, void* d_ws, size_t ws_size,
                              hipStream_t stream) {
    const float* x        = (const float*)d_in[0];
    const int*   ei       = (const int*)d_in[1];
    const float* W0       = (const float*)d_in[2];
    const float* b0       = (const float*)d_in[3];
    const float* W1       = (const float*)d_in[4];
    const float* b1       = (const float*)d_in[5];
    const float* W2       = (const float*)d_in[6];
    const float* b2       = (const float*)d_in[7];
    const float* bn_gamma = (const float*)d_in[8];
    const float* bn_beta  = (const float*)d_in[9];
    float* out = (float*)d_out;

    // workspace carve-up (512B aligned slabs)
    char* p = (char*)d_ws;
    auto alloc = [&](size_t bytes) -> void* {
        void* r = (void*)p;
        p += (bytes + 511) & ~(size_t)511;
        return r;
    };
    float* Hws     = (float*)alloc((size_t)NN * DCAT * 4);
    float* tmpA    = (float*)alloc((size_t)NN * 128 * 4);
    float* tmpB    = (float*)alloc((size_t)NN * 128 * 4);
    int*   deg     = (int*)alloc((size_t)NN * 4);
    float* dinv    = (float*)alloc((size_t)NN * 4);
    int*   ptr     = (int*)alloc((size_t)(NN + 1) * 4);
    int*   cursor  = (int*)alloc((size_t)NN * 4);
    int*   bsum    = (int*)alloc(1024);
    int*   crow    = (int*)alloc((size_t)NE * 4);
    float* cw      = (float*)alloc((size_t)NE * 4);
    float* partial = (float*)alloc((size_t)BN_NBLK * 768 * 4);
    float2* coef   = (float2*)alloc(384 * 8);
    short* Wth     = (short*)alloc((size_t)3 * 128 * 384 * 2);
    short* Wtl     = (short*)alloc((size_t)3 * 128 * 384 * 2);

    // ---- graph preprocessing: degrees, norm weights, CSR by destination ----
    hipMemsetAsync(deg, 0, (size_t)NN * 4, stream);
    count_deg_k<<<(NE + 255) / 256, 256, 0, stream>>>(ei, deg);
    dinv_k<<<(NN + 255) / 256, 256, 0, stream>>>(deg, dinv);
    int nsb = (NN + 1023) / 1024;   // 98
    scan1_k<<<nsb, 1024, 0, stream>>>(deg, ptr, bsum);
    scan2_k<<<1, 64, 0, stream>>>(bsum, nsb);
    scan3_k<<<nsb, 1024, 0, stream>>>(ptr, cursor, bsum);
    scatter_k<<<(NE + 255) / 256, 256, 0, stream>>>(ei, dinv, cursor, crow, cw);

    // ---- layer 0: x (N x 128) -> d_out (N x 384), BN+ReLU in place ----
    run_layer(x, DIN, W0, b0, out, tmpA, tmpB, Wth, Wtl, ptr, crow, cw, stream);
    run_bn(out, bn_gamma, bn_beta, partial, coef, stream);

    // ---- layer 1: d_out -> Hws, BN+ReLU in place ----
    run_layer(out, DCAT, W1, b1, Hws, tmpA, tmpB, Wth, Wtl, ptr, crow, cw, stream);
    run_bn(Hws, bn_gamma + DCAT, bn_beta + DCAT, partial, coef, stream);

    // ---- layer 2: Hws -> d_out (raw concat, no BN) ----
    run_layer(Hws, DCAT, W2, b2, out, tmpA, tmpB, Wth, Wtl, ptr, crow, cw, stream);
}

// Round 3
// 1701.846 us; speedup vs baseline: 1.4131x; 1.1268x over previous
//
#include <hip/hip_runtime.h>
#include <hip/hip_bf16.h>

// ---------------- problem constants ----------------
#define NN 100000      // nodes
#define NE 800000      // edges
#define DIN 128
#define DCAT 384
#define BN_EPS 1e-5

typedef __attribute__((ext_vector_type(8))) short bf16x8;
typedef __attribute__((ext_vector_type(4))) float f32x4;

// ---------------- preprocessing kernels ----------------

__global__ void count_deg_k(const int* __restrict__ ei, int* __restrict__ deg) {
    int i = blockIdx.x * blockDim.x + threadIdx.x;
    if (i < NE) atomicAdd(&deg[ei[NE + i]], 1);   // col = ei[1][e]
}

__global__ void dinv_k(const int* __restrict__ deg, float* __restrict__ dinv) {
    int i = blockIdx.x * blockDim.x + threadIdx.x;
    if (i < NN) {
        int d = deg[i];
        dinv[i] = (d > 0) ? rsqrtf((float)d) : 0.f;
    }
}

__global__ void scan1_k(const int* __restrict__ deg, int* __restrict__ out,
                        int* __restrict__ bsum) {
    __shared__ int s[1024];
    int i = blockIdx.x * 1024 + threadIdx.x;
    int v = (i < NN) ? deg[i] : 0;
    s[threadIdx.x] = v;
    __syncthreads();
    for (int off = 1; off < 1024; off <<= 1) {
        int t = (threadIdx.x >= off) ? s[threadIdx.x - off] : 0;
        __syncthreads();
        s[threadIdx.x] += t;
        __syncthreads();
    }
    if (i < NN) out[i] = s[threadIdx.x] - v;   // exclusive
    if (threadIdx.x == 1023) bsum[blockIdx.x] = s[1023];
}

__global__ void scan2_k(int* __restrict__ bsum, int nb) {
    if (threadIdx.x == 0) {
        int acc = 0;
        for (int b = 0; b < nb; ++b) { int v = bsum[b]; bsum[b] = acc; acc += v; }
    }
}

__global__ void scan3_k(int* __restrict__ ptr, int* __restrict__ cursor,
                        const int* __restrict__ bsum) {
    int i = blockIdx.x * 1024 + threadIdx.x;
    if (i < NN) {
        int p = ptr[i] + bsum[blockIdx.x];
        ptr[i] = p;
        cursor[i] = p;
    }
    if (i == NN) ptr[NN] = NE;
}

__global__ void scatter_k(const int* __restrict__ ei, const float* __restrict__ dinv,
                          int* __restrict__ cursor, int* __restrict__ crow,
                          float* __restrict__ cw) {
    int i = blockIdx.x * blockDim.x + threadIdx.x;
    if (i >= NE) return;
    int r = ei[i];
    int c = ei[NE + i];
    int p = atomicAdd(&cursor[c], 1);
    crow[p] = r;
    cw[p] = dinv[r] * dinv[c];
}

// ---------------- split-bf16 helpers ----------------

__device__ inline void split_trunc(float x, short& hi, short& lo) {
    unsigned u = __builtin_bit_cast(unsigned, x);
    hi = (short)(u >> 16);
    float hf = __builtin_bit_cast(float, u & 0xFFFF0000u);
    __hip_bfloat16 l = __float2bfloat16(x - hf);
    lo = *reinterpret_cast<short*>(&l);
}

// pre-split + transpose weights:  W (3,K,128) -> Wt_hi/lo (3,128,384) [group][col][k]
__global__ void wsplit_k(const float* __restrict__ W, int K,
                         short* __restrict__ Wth, short* __restrict__ Wtl) {
    int i = blockIdx.x * 256 + threadIdx.x;
    if (i >= 3 * K * 128) return;
    int c = i & 127;
    int k = (i >> 7) % K;
    int j = i / (K * 128);
    short h, l;
    split_trunc(W[i], h, l);
    size_t o = (size_t)j * 128 * 384 + (size_t)c * 384 + k;
    Wth[o] = h;
    Wtl[o] = l;
}

// ---------------- MFMA split-bf16 GEMM with fused input-BN+ReLU ----------------
// 1D grid, XCD-chunked swizzle; logical tile = (group j, row-block my).
#define GPITCH 40

__global__ __launch_bounds__(256, 2) void gemm3m_k(
    const float* __restrict__ X, int K,
    const short* __restrict__ Wth, const short* __restrict__ Wtl,
    const float* __restrict__ bias,
    const float2* __restrict__ coef, int use_bn,
    float* __restrict__ o0, float* __restrict__ o1, float* __restrict__ o2) {
    __shared__ short As_h[128 * GPITCH];
    __shared__ short As_l[128 * GPITCH];
    __shared__ short Bs_h[128 * GPITCH];
    __shared__ short Bs_l[128 * GPITCH];

    // bijective XCD-chunked swizzle: consecutive logical ids land on one XCD
    const int nwg = gridDim.x;
    const int id  = blockIdx.x;
    const int q = nwg >> 3, r = nwg & 7;
    const int xcd = id & 7, ii = id >> 3;
    const int swz = (xcd < r ? xcd * (q + 1) : r * (q + 1) + (xcd - r) * q) + ii;
    const int j  = swz % 3;                 // weight group
    const int my = swz / 3;                 // row tile
    const int m0 = my * 128;

    const int t    = threadIdx.x;
    const int lane = t & 63;
    const int wv   = t >> 6;
    const int wr   = (wv >> 1) * 64;
    const int wc   = (wv & 1) * 64;
    const int lr   = lane & 15;
    const int lk   = lane >> 4;

    const short* Wh = Wth + (size_t)j * 128 * 384;
    const short* Wl = Wtl + (size_t)j * 128 * 384;

    f32x4 acc[4][4];
#pragma unroll
    for (int a = 0; a < 4; ++a)
#pragma unroll
        for (int b = 0; b < 4; ++b) acc[a][b] = (f32x4){0.f, 0.f, 0.f, 0.f};

    for (int kb = 0; kb < K; kb += 32) {
        // ---- stage A: 128 rows x 32 k fp32 -> (BN+ReLU) -> hi/lo bf16 in LDS ----
#pragma unroll
        for (int i = 0; i < 4; ++i) {
            int lin = t + i * 256;
            int row = lin >> 3, kq = lin & 7;
            int gr = m0 + row;
            if (gr >= NN) gr = NN - 1;
            float4 a4 = *(const float4*)(X + (size_t)gr * K + kb + kq * 4);
            if (use_bn) {
                int c = kb + kq * 4;
                float2 c0 = coef[c + 0], c1 = coef[c + 1], c2 = coef[c + 2], c3 = coef[c + 3];
                a4.x = fmaxf(a4.x * c0.x + c0.y, 0.f);
                a4.y = fmaxf(a4.y * c1.x + c1.y, 0.f);
                a4.z = fmaxf(a4.z * c2.x + c2.y, 0.f);
                a4.w = fmaxf(a4.w * c3.x + c3.y, 0.f);
            }
            short h0, l0, h1, l1, h2, l2, h3, l3;
            split_trunc(a4.x, h0, l0);
            split_trunc(a4.y, h1, l1);
            split_trunc(a4.z, h2, l2);
            split_trunc(a4.w, h3, l3);
            *(short4*)&As_h[row * GPITCH + kq * 4] = make_short4(h0, h1, h2, h3);
            *(short4*)&As_l[row * GPITCH + kq * 4] = make_short4(l0, l1, l2, l3);
        }
        // ---- stage B ----
#pragma unroll
        for (int i = 0; i < 4; ++i) {
            int lin = t + i * 256;
            int col = lin >> 3, kq = lin & 7;
            short4 bh = *(const short4*)(Wh + (size_t)col * 384 + kb + kq * 4);
            short4 bl = *(const short4*)(Wl + (size_t)col * 384 + kb + kq * 4);
            *(short4*)&Bs_h[col * GPITCH + kq * 4] = bh;
            *(short4*)&Bs_l[col * GPITCH + kq * 4] = bl;
        }
        __syncthreads();

        bf16x8 ah[4], al[4];
#pragma unroll
        for (int mr = 0; mr < 4; ++mr) {
            int rr = wr + mr * 16 + lr;
            ah[mr] = *(const bf16x8*)&As_h[rr * GPITCH + lk * 8];
            al[mr] = *(const bf16x8*)&As_l[rr * GPITCH + lk * 8];
        }
#pragma unroll
        for (int nc = 0; nc < 4; ++nc) {
            int c = wc + nc * 16 + lr;
            bf16x8 bh = *(const bf16x8*)&Bs_h[c * GPITCH + lk * 8];
            bf16x8 bl = *(const bf16x8*)&Bs_l[c * GPITCH + lk * 8];
#pragma unroll
            for (int mr = 0; mr < 4; ++mr) {
                f32x4 a = acc[mr][nc];
                a = __builtin_amdgcn_mfma_f32_16x16x32_bf16(al[mr], bh, a, 0, 0, 0);
                a = __builtin_amdgcn_mfma_f32_16x16x32_bf16(ah[mr], bl, a, 0, 0, 0);
                a = __builtin_amdgcn_mfma_f32_16x16x32_bf16(ah[mr], bh, a, 0, 0, 0);
                acc[mr][nc] = a;
            }
        }
        __syncthreads();
    }

    float* dst;
    int pitch;
    if (j == 0)      { dst = o0; pitch = DCAT; }
    else if (j == 1) { dst = o1; pitch = 128; }
    else             { dst = o2; pitch = 128; }

#pragma unroll
    for (int nc = 0; nc < 4; ++nc) {
        int col = wc + nc * 16 + lr;
        float bv = bias[j * 128 + col];
#pragma unroll
        for (int mr = 0; mr < 4; ++mr) {
            f32x4 a = acc[mr][nc];
#pragma unroll
            for (int rr = 0; rr < 4; ++rr) {
                int row = m0 + wr + mr * 16 + lk * 4 + rr;
                if (row < NN) dst[(size_t)row * pitch + col] = a[rr] + bv;
            }
        }
    }
}

// ---------------- fused dual SpMM: outA = A*inA, outB = A*inB (shared edges) ----
__global__ __launch_bounds__(256) void spmm2_k(
    const int* __restrict__ ptr, const int* __restrict__ rows,
    const float* __restrict__ wv,
    const float* __restrict__ inA, const float* __restrict__ inB,
    float* __restrict__ outA, int poutA,
    float* __restrict__ outB) {
    int wid  = (blockIdx.x * blockDim.x + threadIdx.x) >> 6;
    int lane = threadIdx.x & 63;
    if (wid >= NN) return;
    int e0 = ptr[wid], e1 = ptr[wid + 1];
    float2 aA = make_float2(0.f, 0.f), aB = make_float2(0.f, 0.f);
    int e = e0;
    for (; e + 2 <= e1; e += 2) {
        int   r0 = rows[e],  r1 = rows[e + 1];
        float w0 = wv[e],    w1 = wv[e + 1];
        float2 vA0 = ((const float2*)(inA + (size_t)r0 * 128))[lane];
        float2 vB0 = ((const float2*)(inB + (size_t)r0 * 128))[lane];
        float2 vA1 = ((const float2*)(inA + (size_t)r1 * 128))[lane];
        float2 vB1 = ((const float2*)(inB + (size_t)r1 * 128))[lane];
        aA.x += w0 * vA0.x; aA.y += w0 * vA0.y;
        aB.x += w0 * vB0.x; aB.y += w0 * vB0.y;
        aA.x += w1 * vA1.x; aA.y += w1 * vA1.y;
        aB.x += w1 * vB1.x; aB.y += w1 * vB1.y;
    }
    if (e < e1) {
        int   r0 = rows[e];
        float w0 = wv[e];
        float2 vA0 = ((const float2*)(inA + (size_t)r0 * 128))[lane];
        float2 vB0 = ((const float2*)(inB + (size_t)r0 * 128))[lane];
        aA.x += w0 * vA0.x; aA.y += w0 * vA0.y;
        aB.x += w0 * vB0.x; aB.y += w0 * vB0.y;
    }
    ((float2*)(outA + (size_t)wid * poutA))[lane] = aA;
    ((float2*)(outB + (size_t)wid * 128))[lane] = aB;
}

// ---------------- single SpMM, unroll 4 ----------------
__global__ __launch_bounds__(256) void spmm_k(
    const int* __restrict__ ptr, const int* __restrict__ rows,
    const float* __restrict__ wv, const float* __restrict__ xin, int pin,
    float* __restrict__ xout, int pout) {
    int wid  = (blockIdx.x * blockDim.x + threadIdx.x) >> 6;
    int lane = threadIdx.x & 63;
    if (wid >= NN) return;
    int e0 = ptr[wid], e1 = ptr[wid + 1];
    float2 acc = make_float2(0.f, 0.f);
    int e = e0;
    for (; e + 4 <= e1; e += 4) {
        int   r0 = rows[e],     r1 = rows[e + 1], r2 = rows[e + 2], r3 = rows[e + 3];
        float w0 = wv[e],       w1 = wv[e + 1],   w2 = wv[e + 2],   w3 = wv[e + 3];
        float2 v0 = ((const float2*)(xin + (size_t)r0 * pin))[lane];
        float2 v1 = ((const float2*)(xin + (size_t)r1 * pin))[lane];
        float2 v2 = ((const float2*)(xin + (size_t)r2 * pin))[lane];
        float2 v3 = ((const float2*)(xin + (size_t)r3 * pin))[lane];
        acc.x += w0 * v0.x; acc.y += w0 * v0.y;
        acc.x += w1 * v1.x; acc.y += w1 * v1.y;
        acc.x += w2 * v2.x; acc.y += w2 * v2.y;
        acc.x += w3 * v3.x; acc.y += w3 * v3.y;
    }
    for (; e < e1; ++e) {
        int   r0 = rows[e];
        float w0 = wv[e];
        float2 v0 = ((const float2*)(xin + (size_t)r0 * pin))[lane];
        acc.x += w0 * v0.x; acc.y += w0 * v0.y;
    }
    ((float2*)(xout + (size_t)wid * pout))[lane] = acc;
}

// ---------------- BatchNorm stats (apply is fused into next GEMM) ----------------
#define BN_ROWS 256
#define BN_NBLK ((NN + BN_ROWS - 1) / BN_ROWS)   // 391

__global__ void bn_stats1_k(const float* __restrict__ H, float* __restrict__ partial) {
    int c  = threadIdx.x;                 // 384 threads
    int r0 = blockIdx.x * BN_ROWS;
    int r1 = min(r0 + BN_ROWS, NN);
    float s = 0.f, s2 = 0.f;
    for (int r = r0; r < r1; ++r) {
        float v = H[(size_t)r * DCAT + c];
        s  += v;
        s2 += v * v;
    }
    partial[blockIdx.x * 768 + c]       = s;
    partial[blockIdx.x * 768 + 384 + c] = s2;
}

__global__ void bn_finalize_k(const float* __restrict__ partial,
                              const float* __restrict__ g, const float* __restrict__ b,
                              float2* __restrict__ coef) {
    int c = threadIdx.x;                  // 384 threads
    double s = 0.0, s2 = 0.0;
    for (int i = 0; i < BN_NBLK; ++i) {
        s  += (double)partial[i * 768 + c];
        s2 += (double)partial[i * 768 + 384 + c];
    }
    double mu  = s / (double)NN;
    double var = s2 / (double)NN - mu * mu;
    double inv = 1.0 / sqrt(var + (double)BN_EPS);
    float scale = (float)((double)g[c] * inv);
    float shift = (float)((double)b[c] - mu * (double)g[c] * inv);
    coef[c] = make_float2(scale, shift);
}

// ---------------- host-side orchestration ----------------

static void run_layer(const float* X, int K, const float* W, const float* bias,
                      const float2* coefIn, int use_bn,
                      float* Hout, float* tmpA, float* tmpB, float* tmpC,
                      short* Wth, short* Wtl,
                      const int* ptr, const int* crow, const float* cw,
                      hipStream_t stream) {
    int nw = 3 * K * 128;
    wsplit_k<<<(nw + 255) / 256, 256, 0, stream>>>(W, K, Wth, Wtl);
    int nwg = 3 * ((NN + 127) / 128);
    gemm3m_k<<<nwg, 256, 0, stream>>>(X, K, Wth, Wtl, bias, coefIn, use_bn,
                                      Hout, tmpA, tmpB);
    int sg = (NN * 64 + 255) / 256;   // one wave per node, 4 nodes/block
    spmm2_k<<<sg, 256, 0, stream>>>(ptr, crow, cw, tmpA, tmpB, Hout + 128, DCAT, tmpC);
    spmm_k<<<sg, 256, 0, stream>>>(ptr, crow, cw, tmpC, 128, Hout + 256, DCAT);
}

static void run_bn_stats(const float* H, const float* g, const float* b,
                         float* partial, float2* coef, hipStream_t stream) {
    bn_stats1_k<<<BN_NBLK, 384, 0, stream>>>(H, partial);
    bn_finalize_k<<<1, 384, 0, stream>>>(partial, g, b, coef);
}

extern "C" void kernel_launch(void* const* d_in, const int* in_sizes, int n_in,
                              void* d_out, int out_size, void* d_ws, size_t ws_size,
                              hipStream_t stream) {
    const float* x        = (const float*)d_in[0];
    const int*   ei       = (const int*)d_in[1];
    const float* W0       = (const float*)d_in[2];
    const float* b0       = (const float*)d_in[3];
    const float* W1       = (const float*)d_in[4];
    const float* b1       = (const float*)d_in[5];
    const float* W2       = (const float*)d_in[6];
    const float* b2       = (const float*)d_in[7];
    const float* bn_gamma = (const float*)d_in[8];
    const float* bn_beta  = (const float*)d_in[9];
    float* out = (float*)d_out;

    // workspace carve-up (512B aligned slabs)
    char* p = (char*)d_ws;
    auto alloc = [&](size_t bytes) -> void* {
        void* r = (void*)p;
        p += (bytes + 511) & ~(size_t)511;
        return r;
    };
    float* Hws     = (float*)alloc((size_t)NN * DCAT * 4);
    float* tmpA    = (float*)alloc((size_t)NN * 128 * 4);
    float* tmpB    = (float*)alloc((size_t)NN * 128 * 4);
    int*   deg     = (int*)alloc((size_t)NN * 4);
    float* dinv    = (float*)alloc((size_t)NN * 4);
    int*   ptr     = (int*)alloc((size_t)(NN + 1) * 4);
    int*   cursor  = (int*)alloc((size_t)NN * 4);
    int*   bsum    = (int*)alloc(1024);
    int*   crow    = (int*)alloc((size_t)NE * 4);
    float* cw      = (float*)alloc((size_t)NE * 4);
    float* partial = (float*)alloc((size_t)BN_NBLK * 768 * 4);
    float2* coef   = (float2*)alloc(384 * 8);
    short* Wth     = (short*)alloc((size_t)3 * 128 * 384 * 2);
    short* Wtl     = (short*)alloc((size_t)3 * 128 * 384 * 2);

    // ---- graph preprocessing ----
    hipMemsetAsync(deg, 0, (size_t)NN * 4, stream);
    count_deg_k<<<(NE + 255) / 256, 256, 0, stream>>>(ei, deg);
    dinv_k<<<(NN + 255) / 256, 256, 0, stream>>>(deg, dinv);
    int nsb = (NN + 1023) / 1024;   // 98
    scan1_k<<<nsb, 1024, 0, stream>>>(deg, ptr, bsum);
    scan2_k<<<1, 64, 0, stream>>>(bsum, nsb);
    scan3_k<<<nsb, 1024, 0, stream>>>(ptr, cursor, bsum);
    scatter_k<<<(NE + 255) / 256, 256, 0, stream>>>(ei, dinv, cursor, crow, cw);

    // Layer 0: X = x (no BN on input). tmpC = Hws (free until layer-1 gemm writes it).
    run_layer(x, DIN, W0, b0, coef, 0, out, tmpA, tmpB, Hws,
              Wth, Wtl, ptr, crow, cw, stream);
    run_bn_stats(out, bn_gamma, bn_beta, partial, coef, stream);

    // Layer 1: X = out with fused BN+ReLU. After gemm, `out` is dead -> tmpC = out.
    run_layer(out, DCAT, W1, b1, coef, 1, Hws, tmpA, tmpB, out,
              Wth, Wtl, ptr, crow, cw, stream);
    run_bn_stats(Hws, bn_gamma + DCAT, bn_beta + DCAT, partial, coef, stream);

    // Layer 2: X = Hws with fused BN+ReLU. After gemm, Hws dead -> tmpC = Hws.
    run_layer(Hws, DCAT, W2, b2, coef, 1, out, tmpA, tmpB, Hws,
              Wth, Wtl, ptr, crow, cw, stream);
}